// Round 6
// baseline (41.676 us; speedup 1.0000x reference)
//
#include <hip/hip_runtime.h>
#include <math.h>

// QuBlur: x[4096,4096] f32 -> out[2,4096,4096] f32 (real, imag).
// Per 4x4 block: B' = U (B/||B||_F) U^H ; then global /1024 (analytic gnorm:
// normalized blocks have unit Frobenius norm, unitary conjugation preserves
// it -> gnorm = 1024; error ~1e-9 abs vs 1.56e-5 threshold).
//
// R2: fused U-computation (thread 0 per wg -> LDS broadcast), one dispatch.
// R5: nt stores proven neutral; reverted.
// R6: strip mapping — each wave owns a 4KB-wide strip (4 blocks/thread at
//     64-block stride) so reads/writes form contiguous 4KB runs per row per
//     plane (DRAM page locality) and 16 loads/thread are in flight (MLP).

#define NQ   4096
#define NBLK 1024

typedef float f32x4 __attribute__((ext_vector_type(4)));

__global__ __launch_bounds__(256) void qblur_main(const float* __restrict__ x,
                                                  const float* __restrict__ wt,
                                                  float* __restrict__ out) {
    __shared__ float Uld[32];   // [0:16) = U real, [16:32) = U imag

    if (threadIdx.x == 0) {
        const float W_MUL = 0.6324555320336759f;  // np.float32(sqrt(2)*5^-0.5)
        float c[5], s[5];
        #pragma unroll
        for (int i = 0; i < 5; ++i) {
            float w = wt[i] * W_MUL;
            c[i] = cosf(0.5f * w);
            s[i] = sinf(0.5f * w);
        }
        float A1[4] = {c[0], -s[0], s[0], c[0]};
        float B1[4] = {c[1], -s[1], s[1], c[1]};
        float A3[4] = {c[3], -s[3], s[3], c[3]};
        float B3[4] = {c[4], -s[4], s[4], c[4]};
        float g1[16], g3[16];
        for (int i = 0; i < 2; ++i)
            for (int j = 0; j < 2; ++j)
                for (int k = 0; k < 2; ++k)
                    for (int l = 0; l < 2; ++l) {
                        g1[(2*i+j)*4 + 2*k+l] = A1[2*i+k] * B1[2*j+l];
                        g3[(2*i+j)*4 + 2*k+l] = A3[2*i+k] * B3[2*j+l];
                    }
        // g2 = cos(w2/2) I - i sin(w2/2) * (Y (x) Y)
        float g2r[16], g2i[16];
        for (int i = 0; i < 16; ++i) { g2r[i] = 0.f; g2i[i] = 0.f; }
        g2r[0] = c[2]; g2r[5] = c[2]; g2r[10] = c[2]; g2r[15] = c[2];
        g2i[3] = s[2]; g2i[6] = -s[2]; g2i[9] = -s[2]; g2i[12] = s[2];
        // T = g3 @ g2 (left-assoc like the reference), then U = T @ g1
        float Tr[16], Ti[16];
        for (int i = 0; i < 4; ++i)
            for (int j = 0; j < 4; ++j) {
                float ar = 0.f, ai = 0.f;
                for (int k = 0; k < 4; ++k) {
                    ar = fmaf(g3[4*i+k], g2r[4*k+j], ar);
                    ai = fmaf(g3[4*i+k], g2i[4*k+j], ai);
                }
                Tr[4*i+j] = ar; Ti[4*i+j] = ai;
            }
        for (int i = 0; i < 4; ++i)
            for (int j = 0; j < 4; ++j) {
                float ar = 0.f, ai = 0.f;
                for (int k = 0; k < 4; ++k) {
                    ar = fmaf(Tr[4*i+k], g1[4*k+j], ar);
                    ai = fmaf(Ti[4*i+k], g1[4*k+j], ai);
                }
                Uld[4*i+j]      = ar;
                Uld[16 + 4*i+j] = ai;
            }
    }
    __syncthreads();

    const int lane = threadIdx.x & 63;
    const int wave = threadIdx.x >> 6;
    const int strip = blockIdx.x * 4 + wave;   // 0 .. 4095
    const int a = strip >> 2;                  // block-row 0..1023
    const int q = strip & 3;                   // 4KB quarter of the row
    const size_t rowbase = (size_t)(a * 4) * NQ;

    // 16 loads issued up front: 4 blocks (k) x 4 rows (r), each f32x4.
    // For fixed (k,r): 64 lanes cover a contiguous 1KB; k=0..3 chain into
    // one 4KB run per row.
    f32x4 d[4][4];
    #pragma unroll
    for (int k = 0; k < 4; ++k) {
        const float* p = x + rowbase + (size_t)(q * 1024 + k * 256 + lane * 4);
        #pragma unroll
        for (int r = 0; r < 4; ++r)
            d[k][r] = *(const f32x4*)(p + (size_t)r * NQ);
    }

    // uniform-address LDS reads -> broadcast, no bank conflicts
    float Ur[4][4], Ui[4][4];
    #pragma unroll
    for (int i = 0; i < 4; ++i)
        #pragma unroll
        for (int j = 0; j < 4; ++j) {
            Ur[i][j] = Uld[4*i+j];
            Ui[i][j] = Uld[16 + 4*i+j];
        }

    float* outr = out + rowbase;
    float* outi = out + (size_t)NQ * NQ + rowbase;

    #pragma unroll
    for (int k = 0; k < 4; ++k) {
        const int col = q * 1024 + k * 256 + lane * 4;

        float ss = 0.f;
        #pragma unroll
        for (int r = 0; r < 4; ++r)
            #pragma unroll
            for (int c = 0; c < 4; ++c) ss = fmaf(d[k][r][c], d[k][r][c], ss);
        const float norm = sqrtf(ss);
        const float scale = (ss > 0.f) ? 1.0f / (norm * 1024.0f) : 0.0f;

        // t = U B U^H; row r of t depends only on row r of M = U B
        #pragma unroll
        for (int r = 0; r < 4; ++r) {
            float mr[4], mi[4];
            #pragma unroll
            for (int cc = 0; cc < 4; ++cc) {
                float ar = 0.f, ai = 0.f;
                #pragma unroll
                for (int kk = 0; kk < 4; ++kk) {
                    ar = fmaf(Ur[r][kk], d[k][kk][cc], ar);
                    ai = fmaf(Ui[r][kk], d[k][kk][cc], ai);
                }
                mr[cc] = ar; mi[cc] = ai;
            }
            f32x4 trv, tiv;
            #pragma unroll
            for (int cc = 0; cc < 4; ++cc) {
                float tr = 0.f, ti = 0.f;
                #pragma unroll
                for (int kk = 0; kk < 4; ++kk) {
                    // (U^H)[kk][cc] = Ur[cc][kk] - i Ui[cc][kk]
                    tr = fmaf(mr[kk], Ur[cc][kk], tr);
                    tr = fmaf(mi[kk], Ui[cc][kk], tr);
                    ti = fmaf(mi[kk], Ur[cc][kk], ti);
                    ti = fmaf(-mr[kk], Ui[cc][kk], ti);
                }
                trv[cc] = tr * scale;
                tiv[cc] = ti * scale;
            }
            *(f32x4*)(outr + (size_t)r * NQ + col) = trv;
            *(f32x4*)(outi + (size_t)r * NQ + col) = tiv;
        }
    }
}

extern "C" void kernel_launch(void* const* d_in, const int* in_sizes, int n_in,
                              void* d_out, int out_size, void* d_ws, size_t ws_size,
                              hipStream_t stream) {
    const float* x  = (const float*)d_in[0];
    const float* wt = (const float*)d_in[1];
    float* out = (float*)d_out;

    // 1024 wgs x 256 threads; each wave handles one 4-row x 4KB strip
    qblur_main<<<NBLK, 256, 0, stream>>>(x, wt, out);
}

// Round 7
// 36.686 us; speedup vs baseline: 1.1360x; 1.1360x over previous
//
#include <hip/hip_runtime.h>
#include <math.h>

// QuBlur: x[4096,4096] f32 -> out[2,4096,4096] f32 (real, imag).
// Per 4x4 block: B' = U (B/||B||_F) U^H ; then global /1024 (analytic gnorm:
// normalized blocks have unit Frobenius norm, unitary conjugation preserves
// it -> gnorm = 1024; error ~1e-9 abs vs 1.56e-5 threshold).
//
// R2: fused U-computation (thread 0 per wg -> LDS broadcast), one dispatch.
// R5: nt stores proven neutral; reverted.
// R6: 4 blocks/thread strip FAILED (-15%): 1024 WGs -> 8 waves/CU resident,
//     latency not hidden. Lesson: keep >= 8192 waves.
// R7: 2 blocks/thread: 2048 WGs = 32 waves/CU demand (~20-24 resident at
//     ~90 VGPR) AND 2KB contiguous runs per row per plane + 8-deep MLP.

#define NQ   4096
#define NBLK 1024

typedef float f32x4 __attribute__((ext_vector_type(4)));

__global__ __launch_bounds__(256) void qblur_main(const float* __restrict__ x,
                                                  const float* __restrict__ wt,
                                                  float* __restrict__ out) {
    __shared__ float Uld[32];   // [0:16) = U real, [16:32) = U imag

    if (threadIdx.x == 0) {
        const float W_MUL = 0.6324555320336759f;  // np.float32(sqrt(2)*5^-0.5)
        float c[5], s[5];
        #pragma unroll
        for (int i = 0; i < 5; ++i) {
            float w = wt[i] * W_MUL;
            c[i] = cosf(0.5f * w);
            s[i] = sinf(0.5f * w);
        }
        float A1[4] = {c[0], -s[0], s[0], c[0]};
        float B1[4] = {c[1], -s[1], s[1], c[1]};
        float A3[4] = {c[3], -s[3], s[3], c[3]};
        float B3[4] = {c[4], -s[4], s[4], c[4]};
        float g1[16], g3[16];
        for (int i = 0; i < 2; ++i)
            for (int j = 0; j < 2; ++j)
                for (int k = 0; k < 2; ++k)
                    for (int l = 0; l < 2; ++l) {
                        g1[(2*i+j)*4 + 2*k+l] = A1[2*i+k] * B1[2*j+l];
                        g3[(2*i+j)*4 + 2*k+l] = A3[2*i+k] * B3[2*j+l];
                    }
        // g2 = cos(w2/2) I - i sin(w2/2) * (Y (x) Y)
        float g2r[16], g2i[16];
        for (int i = 0; i < 16; ++i) { g2r[i] = 0.f; g2i[i] = 0.f; }
        g2r[0] = c[2]; g2r[5] = c[2]; g2r[10] = c[2]; g2r[15] = c[2];
        g2i[3] = s[2]; g2i[6] = -s[2]; g2i[9] = -s[2]; g2i[12] = s[2];
        // T = g3 @ g2 (left-assoc like the reference), then U = T @ g1
        float Tr[16], Ti[16];
        for (int i = 0; i < 4; ++i)
            for (int j = 0; j < 4; ++j) {
                float ar = 0.f, ai = 0.f;
                for (int k = 0; k < 4; ++k) {
                    ar = fmaf(g3[4*i+k], g2r[4*k+j], ar);
                    ai = fmaf(g3[4*i+k], g2i[4*k+j], ai);
                }
                Tr[4*i+j] = ar; Ti[4*i+j] = ai;
            }
        for (int i = 0; i < 4; ++i)
            for (int j = 0; j < 4; ++j) {
                float ar = 0.f, ai = 0.f;
                for (int k = 0; k < 4; ++k) {
                    ar = fmaf(Tr[4*i+k], g1[4*k+j], ar);
                    ai = fmaf(Ti[4*i+k], g1[4*k+j], ai);
                }
                Uld[4*i+j]      = ar;
                Uld[16 + 4*i+j] = ai;
            }
    }
    __syncthreads();

    const int lane = threadIdx.x & 63;
    const int wave = threadIdx.x >> 6;
    const int strip = blockIdx.x * 4 + wave;   // 0 .. 8191
    const int a = strip >> 3;                  // block-row 0..1023
    const int h = strip & 7;                   // 2KB eighth of the row
    const size_t rowbase = (size_t)(a * 4) * NQ;

    // 8 loads in flight: 2 blocks (k) x 4 rows (r); for fixed (k,r) the wave
    // covers a contiguous 1KB, k=0..1 chain into a 2KB run per row.
    f32x4 d[2][4];
    #pragma unroll
    for (int k = 0; k < 2; ++k) {
        const float* p = x + rowbase + (size_t)(h * 512 + k * 256 + lane * 4);
        #pragma unroll
        for (int r = 0; r < 4; ++r)
            d[k][r] = *(const f32x4*)(p + (size_t)r * NQ);
    }

    // uniform-address LDS reads -> broadcast, no bank conflicts
    float Ur[4][4], Ui[4][4];
    #pragma unroll
    for (int i = 0; i < 4; ++i)
        #pragma unroll
        for (int j = 0; j < 4; ++j) {
            Ur[i][j] = Uld[4*i+j];
            Ui[i][j] = Uld[16 + 4*i+j];
        }

    float* outr = out + rowbase;
    float* outi = out + (size_t)NQ * NQ + rowbase;

    #pragma unroll
    for (int k = 0; k < 2; ++k) {
        const int col = h * 512 + k * 256 + lane * 4;

        float ss = 0.f;
        #pragma unroll
        for (int r = 0; r < 4; ++r)
            #pragma unroll
            for (int c = 0; c < 4; ++c) ss = fmaf(d[k][r][c], d[k][r][c], ss);
        const float norm = sqrtf(ss);
        const float scale = (ss > 0.f) ? 1.0f / (norm * 1024.0f) : 0.0f;

        // t = U B U^H; row r of t depends only on row r of M = U B
        #pragma unroll
        for (int r = 0; r < 4; ++r) {
            float mr[4], mi[4];
            #pragma unroll
            for (int cc = 0; cc < 4; ++cc) {
                float ar = 0.f, ai = 0.f;
                #pragma unroll
                for (int kk = 0; kk < 4; ++kk) {
                    ar = fmaf(Ur[r][kk], d[k][kk][cc], ar);
                    ai = fmaf(Ui[r][kk], d[k][kk][cc], ai);
                }
                mr[cc] = ar; mi[cc] = ai;
            }
            f32x4 trv, tiv;
            #pragma unroll
            for (int cc = 0; cc < 4; ++cc) {
                float tr = 0.f, ti = 0.f;
                #pragma unroll
                for (int kk = 0; kk < 4; ++kk) {
                    // (U^H)[kk][cc] = Ur[cc][kk] - i Ui[cc][kk]
                    tr = fmaf(mr[kk], Ur[cc][kk], tr);
                    tr = fmaf(mi[kk], Ui[cc][kk], tr);
                    ti = fmaf(mi[kk], Ur[cc][kk], ti);
                    ti = fmaf(-mr[kk], Ui[cc][kk], ti);
                }
                trv[cc] = tr * scale;
                tiv[cc] = ti * scale;
            }
            *(f32x4*)(outr + (size_t)r * NQ + col) = trv;
            *(f32x4*)(outi + (size_t)r * NQ + col) = tiv;
        }
    }
}

extern "C" void kernel_launch(void* const* d_in, const int* in_sizes, int n_in,
                              void* d_out, int out_size, void* d_ws, size_t ws_size,
                              hipStream_t stream) {
    const float* x  = (const float*)d_in[0];
    const float* wt = (const float*)d_in[1];
    float* out = (float*)d_out;

    // 2048 wgs x 256 threads; each wave handles a 4-row x 2KB strip
    qblur_main<<<2 * NBLK, 256, 0, stream>>>(x, wt, out);
}

// Round 8
// 36.234 us; speedup vs baseline: 1.1502x; 1.0125x over previous
//
#include <hip/hip_runtime.h>
#include <math.h>

// QuBlur: x[4096,4096] f32 -> out[2,4096,4096] f32 (real, imag).
// Per 4x4 block: B' = U (B/||B||_F) U^H ; then global /1024.
//
// gnorm identity: normalized blocks have ||.||_F = 1, unitary conjugation
// preserves it -> gnorm = 1024 analytically (error ~1e-9 abs vs 1.56e-5
// threshold). Saves the second full pass over the 128 MiB output.
//
// Final config (R8 = revert to R5, the measured optimum):
//   - single fused dispatch; U built by thread 0 -> LDS broadcast
//   - one thread per 4x4 block, 4096 wgs x 256 (max occupancy)
//   - plain f32x4 stores (nt proven neutral in R5)
// Mapping ladder measured: R5 1KB-runs/full-occ = 36.25us < R7 2KB = 36.69
// < R6 4KB/low-occ = 41.68. Traffic floor 201MB @ 6.29TB/s copy ceiling
// + ~3us replay overhead ~= 35us -> R5 is within ~3.5% of the roofline.

#define NQ   4096
#define NBLK 1024

typedef float f32x4 __attribute__((ext_vector_type(4)));

__global__ __launch_bounds__(256) void qblur_main(const float* __restrict__ x,
                                                  const float* __restrict__ wt,
                                                  float* __restrict__ out) {
    __shared__ float Uld[32];   // [0:16) = U real, [16:32) = U imag

    if (threadIdx.x == 0) {
        const float W_MUL = 0.6324555320336759f;  // np.float32(sqrt(2)*5^-0.5)
        float c[5], s[5];
        #pragma unroll
        for (int i = 0; i < 5; ++i) {
            float w = wt[i] * W_MUL;
            c[i] = cosf(0.5f * w);
            s[i] = sinf(0.5f * w);
        }
        float A1[4] = {c[0], -s[0], s[0], c[0]};
        float B1[4] = {c[1], -s[1], s[1], c[1]};
        float A3[4] = {c[3], -s[3], s[3], c[3]};
        float B3[4] = {c[4], -s[4], s[4], c[4]};
        float g1[16], g3[16];
        for (int i = 0; i < 2; ++i)
            for (int j = 0; j < 2; ++j)
                for (int k = 0; k < 2; ++k)
                    for (int l = 0; l < 2; ++l) {
                        g1[(2*i+j)*4 + 2*k+l] = A1[2*i+k] * B1[2*j+l];
                        g3[(2*i+j)*4 + 2*k+l] = A3[2*i+k] * B3[2*j+l];
                    }
        // g2 = cos(w2/2) I - i sin(w2/2) * (Y (x) Y)
        float g2r[16], g2i[16];
        for (int i = 0; i < 16; ++i) { g2r[i] = 0.f; g2i[i] = 0.f; }
        g2r[0] = c[2]; g2r[5] = c[2]; g2r[10] = c[2]; g2r[15] = c[2];
        g2i[3] = s[2]; g2i[6] = -s[2]; g2i[9] = -s[2]; g2i[12] = s[2];
        // T = g3 @ g2 (left-assoc like the reference), then U = T @ g1
        float Tr[16], Ti[16];
        for (int i = 0; i < 4; ++i)
            for (int j = 0; j < 4; ++j) {
                float ar = 0.f, ai = 0.f;
                for (int k = 0; k < 4; ++k) {
                    ar = fmaf(g3[4*i+k], g2r[4*k+j], ar);
                    ai = fmaf(g3[4*i+k], g2i[4*k+j], ai);
                }
                Tr[4*i+j] = ar; Ti[4*i+j] = ai;
            }
        for (int i = 0; i < 4; ++i)
            for (int j = 0; j < 4; ++j) {
                float ar = 0.f, ai = 0.f;
                for (int k = 0; k < 4; ++k) {
                    ar = fmaf(Tr[4*i+k], g1[4*k+j], ar);
                    ai = fmaf(Ti[4*i+k], g1[4*k+j], ai);
                }
                Uld[4*i+j]      = ar;
                Uld[16 + 4*i+j] = ai;
            }
    }
    __syncthreads();

    const int tid = blockIdx.x * 256 + threadIdx.x;   // 0 .. 1048575
    const int a = tid >> 10;                          // block row
    const int b = tid & (NBLK - 1);                   // block col
    const size_t base = (size_t)(a * 4) * NQ + (size_t)b * 4;

    const float* xp = x + base;
    const float4 r0 = *(const float4*)(xp);
    const float4 r1 = *(const float4*)(xp + NQ);
    const float4 r2 = *(const float4*)(xp + 2 * NQ);
    const float4 r3 = *(const float4*)(xp + 3 * NQ);
    float B[4][4] = {
        {r0.x, r0.y, r0.z, r0.w},
        {r1.x, r1.y, r1.z, r1.w},
        {r2.x, r2.y, r2.z, r2.w},
        {r3.x, r3.y, r3.z, r3.w}};

    float ss = 0.f;
    #pragma unroll
    for (int i = 0; i < 4; ++i)
        #pragma unroll
        for (int j = 0; j < 4; ++j) ss = fmaf(B[i][j], B[i][j], ss);
    const float norm = sqrtf(ss);
    const float scale = (ss > 0.f) ? 1.0f / (norm * 1024.0f) : 0.0f;

    // uniform-address LDS reads -> broadcast, no bank conflicts
    float Ur[4][4], Ui[4][4];
    #pragma unroll
    for (int i = 0; i < 4; ++i)
        #pragma unroll
        for (int j = 0; j < 4; ++j) {
            Ur[i][j] = Uld[4*i+j];
            Ui[i][j] = Uld[16 + 4*i+j];
        }

    float* outr = out + base;
    float* outi = out + (size_t)NQ * NQ + base;

    // t = U B U^H; row r of t depends only on row r of M = U B
    #pragma unroll
    for (int r = 0; r < 4; ++r) {
        float mr[4], mi[4];
        #pragma unroll
        for (int cc = 0; cc < 4; ++cc) {
            float ar = 0.f, ai = 0.f;
            #pragma unroll
            for (int k = 0; k < 4; ++k) {
                ar = fmaf(Ur[r][k], B[k][cc], ar);
                ai = fmaf(Ui[r][k], B[k][cc], ai);
            }
            mr[cc] = ar; mi[cc] = ai;
        }
        f32x4 trv, tiv;
        #pragma unroll
        for (int cc = 0; cc < 4; ++cc) {
            float tr = 0.f, ti = 0.f;
            #pragma unroll
            for (int k = 0; k < 4; ++k) {
                // (U^H)[k][cc] = Ur[cc][k] - i Ui[cc][k]
                tr = fmaf(mr[k], Ur[cc][k], tr);
                tr = fmaf(mi[k], Ui[cc][k], tr);
                ti = fmaf(mi[k], Ur[cc][k], ti);
                ti = fmaf(-mr[k], Ui[cc][k], ti);
            }
            trv[cc] = tr * scale;
            tiv[cc] = ti * scale;
        }
        *(f32x4*)(outr + (size_t)r * NQ) = trv;
        *(f32x4*)(outi + (size_t)r * NQ) = tiv;
    }
}

extern "C" void kernel_launch(void* const* d_in, const int* in_sizes, int n_in,
                              void* d_out, int out_size, void* d_ws, size_t ws_size,
                              hipStream_t stream) {
    const float* x  = (const float*)d_in[0];
    const float* wt = (const float*)d_in[1];
    float* out = (float*)d_out;

    const int n_threads = NBLK * NBLK;          // one thread per 4x4 block
    qblur_main<<<n_threads / 256, 256, 0, stream>>>(x, wt, out);
}